// Round 9
// baseline (235.580 us; speedup 1.0000x reference)
//
#include <hip/hip_runtime.h>
#include <hip/hip_bf16.h>

typedef __attribute__((ext_vector_type(8))) short bf16x8;
typedef __attribute__((ext_vector_type(8))) unsigned short u16x8;
typedef __attribute__((ext_vector_type(4))) float f32x4;

#define NEG_INF (-__builtin_inff())
#define SPLIT 4
#define QSCALE (0.125f * 1.4426950408889634f)   // 1/sqrt(64) * log2(e); exp2 domain
#define CONST_M 12.0f                            // safe upper bound on exp2-domain scores

static __device__ __forceinline__ unsigned short f2bf(float x) {
  union { float f; unsigned u; } v; v.f = x;
  unsigned r = (v.u + 0x7fffu + ((v.u >> 16) & 1u)) >> 16;
  return (unsigned short)r;
}

// ---- KV f32 -> bf16 row-major + bf16 blocked-transpose kvt[blk][64][32];
// ---- also computes segment boundaries (fused): seg[b]=start, seg[8+b]=end ----
__global__ void prep_kv_kernel(const float* __restrict__ kv, const int* __restrict__ kvc,
                               unsigned short* __restrict__ kvb, unsigned short* __restrict__ kvt,
                               int* __restrict__ seg, int nkv) {
  __shared__ unsigned short tile[32][64];
  const int nb8 = gridDim.x >> 3;
  const int bp = ((gridDim.x & 7) == 0) ? ((blockIdx.x & 7) * nb8 + (blockIdx.x >> 3))
                                        : blockIdx.x;
  const int kv0 = bp * 32;
  const int t = threadIdx.x;
  if (t < 32) {
    int i = kv0 + t;
    if (i < nkv) {
      int c = kvc[i];
      int cp = (i == 0) ? -1 : kvc[i - 1];
      if (c != cp) {
        for (int b = cp + 1; b <= c; ++b) seg[b] = i;
        if (i == 0) for (int b = 0; b < c; ++b) seg[8 + b] = 0;
      }
      int cn = (i == nkv - 1) ? 8 : kvc[i + 1];
      if (c != cn) {
        for (int b = c; b < cn; ++b) seg[8 + b] = i + 1;
        if (i == nkv - 1) for (int b = c + 1; b < 8; ++b) seg[b] = nkv;
      }
    }
  }
  int r = (t * 8) >> 6;
  int c = (t * 8) & 63;
  const float4* src = (const float4*)(kv + (size_t)(kv0 + r) * 64 + c);
  float4 a = src[0], b = src[1];
  u16x8 v;
  v[0] = f2bf(a.x); v[1] = f2bf(a.y); v[2] = f2bf(a.z); v[3] = f2bf(a.w);
  v[4] = f2bf(b.x); v[5] = f2bf(b.y); v[6] = f2bf(b.z); v[7] = f2bf(b.w);
  *(u16x8*)&tile[r][c] = v;
  *(u16x8*)(kvb + (size_t)(kv0 + r) * 64 + c) = v;
  __syncthreads();
  int d = t & 63;
  int k0 = (t >> 6) * 8;
  u16x8 w;
#pragma unroll
  for (int j = 0; j < 8; ++j) w[j] = tile[k0 + j][d];
  *(u16x8*)(kvt + (size_t)bp * 2048 + d * 32 + k0) = w;
}

// keep all 4 VGPRs of a 16B fragment alive (prevents load narrowing/DCE)
#define KEEP4(x) { f32x4 _k = *(const f32x4*)&(x);                             \
  asm volatile("" :: "v"(_k[0]), "v"(_k[1]), "v"(_k[2]), "v"(_k[3])); }

#define LOADK(P, kvx)                                                          \
  {                                                                            \
    const unsigned short* kb_ = kvb + (((size_t)((kvx) + rowoff)) << 6) + g8;  \
    k##P##0 = *(const bf16x8*)(kb_);                                           \
    k##P##1 = *(const bf16x8*)(kb_ + 32);                                      \
    k##P##2 = *(const bf16x8*)(kb_ + 256);                                     \
    k##P##3 = *(const bf16x8*)(kb_ + 256 + 32);                                \
  }

#define LOADV(P, kvx)                                                          \
  {                                                                            \
    const unsigned short* vb_ = kvt + (((size_t)(kvx) >> 5) << 11) + q16 * 32 + g8; \
    v##P##0 = *(const bf16x8*)(vb_);                                           \
    v##P##1 = *(const bf16x8*)(vb_ + 512);                                     \
    v##P##2 = *(const bf16x8*)(vb_ + 1024);                                    \
    v##P##3 = *(const bf16x8*)(vb_ + 1536);                                    \
  }

// V==0: full; V==1: no-softmax (loads+MFMA+pack); V==2: loads-only
#define DIAG_STEP(P, kvx)                                                      \
  {                                                                            \
    const int kv0_ = (kvx);                                                    \
    if constexpr (V == 2) {                                                    \
      (void)kv0_;                                                              \
      KEEP4(k##P##0); KEEP4(k##P##1); KEEP4(k##P##2); KEEP4(k##P##3);          \
      KEEP4(v##P##0); KEEP4(v##P##1); KEEP4(v##P##2); KEEP4(v##P##3);          \
    } else {                                                                   \
      f32x4 z_ = {0, 0, 0, 0};                                                 \
      __builtin_amdgcn_s_setprio(1);                                           \
      f32x4 sT0 = __builtin_amdgcn_mfma_f32_16x16x32_bf16(k##P##0, qf0, z_, 0, 0, 0); \
      sT0 = __builtin_amdgcn_mfma_f32_16x16x32_bf16(k##P##1, qf1, sT0, 0, 0, 0); \
      f32x4 sT1 = __builtin_amdgcn_mfma_f32_16x16x32_bf16(k##P##2, qf0, z_, 0, 0, 0); \
      sT1 = __builtin_amdgcn_mfma_f32_16x16x32_bf16(k##P##3, qf1, sT1, 0, 0, 0); \
      __builtin_amdgcn_s_setprio(0);                                           \
      float e_[8];                                                             \
      if constexpr (V == 0) {                                                  \
        float v_[8];                                                           \
        const bool full_ = uniformb && (kv0_ >= kv_lo) && (kv0_ + 32 <= kv_hi); \
        if (full_) {                                                           \
          _Pragma("unroll") for (int r = 0; r < 4; ++r) {                      \
            v_[r] = sT0[r]; v_[4 + r] = sT1[r];                                \
          }                                                                    \
        } else {                                                               \
          const int k0_ = kv0_ + g8;                                           \
          _Pragma("unroll") for (int r = 0; r < 4; ++r) {                      \
            v_[r]     = (k0_ + r     >= lo_q && k0_ + r     < hi_q) ? sT0[r] : NEG_INF; \
            v_[4 + r] = (k0_ + r + 4 >= lo_q && k0_ + r + 4 < hi_q) ? sT1[r] : NEG_INF; \
          }                                                                    \
        }                                                                      \
        float t_ = fmaxf(fmaxf(fmaxf(v_[0], v_[1]), fmaxf(v_[2], v_[3])),      \
                         fmaxf(fmaxf(v_[4], v_[5]), fmaxf(v_[6], v_[7])));     \
        if (__builtin_expect(__any(t_ > m), 0)) {                              \
          float tt_ = fmaxf(t_, __shfl_xor(t_, 16));                           \
          tt_ = fmaxf(tt_, __shfl_xor(tt_, 32));                               \
          float mn_ = fmaxf(m, tt_);                                           \
          float f_ = __builtin_exp2f(m - mn_);                                 \
          l *= f_;                                                             \
          _Pragma("unroll") for (int r = 0; r < 4; ++r) {                      \
            acc0[r] *= f_; acc1[r] *= f_; acc2[r] *= f_; acc3[r] *= f_;        \
          }                                                                    \
          m = mn_;                                                             \
        }                                                                      \
        _Pragma("unroll") for (int i = 0; i < 8; ++i)                          \
          e_[i] = __builtin_exp2f(v_[i] - m);                                  \
        l += (((e_[0] + e_[1]) + (e_[2] + e_[3])) +                            \
              ((e_[4] + e_[5]) + (e_[6] + e_[7])));                            \
      } else {                                                                 \
        _Pragma("unroll") for (int r = 0; r < 4; ++r) {                        \
          e_[r] = sT0[r]; e_[4 + r] = sT1[r];                                  \
        }                                                                      \
      }                                                                        \
      bf16x8 pa_;                                                              \
      _Pragma("unroll") for (int j = 0; j < 8; ++j) pa_[j] = (short)f2bf(e_[j]); \
      __builtin_amdgcn_s_setprio(1);                                           \
      acc0 = __builtin_amdgcn_mfma_f32_16x16x32_bf16(v##P##0, pa_, acc0, 0, 0, 0); \
      acc1 = __builtin_amdgcn_mfma_f32_16x16x32_bf16(v##P##1, pa_, acc1, 0, 0, 0); \
      acc2 = __builtin_amdgcn_mfma_f32_16x16x32_bf16(v##P##2, pa_, acc2, 0, 0, 0); \
      acc3 = __builtin_amdgcn_mfma_f32_16x16x32_bf16(v##P##3, pa_, acc3, 0, 0, 0); \
      __builtin_amdgcn_s_setprio(0);                                           \
    }                                                                          \
  }

template<int V, int REPS>
__global__ __launch_bounds__(256, 2) void attn_kernel(
    const float* __restrict__ qf,            // [n1][64] f32
    const unsigned short* __restrict__ kvb,  // [n2][64] bf16
    const unsigned short* __restrict__ kvt,  // [n2/32][64][32] bf16
    const int* __restrict__ qc,
    const int* __restrict__ seg,
    float* __restrict__ out, int n2)
{
  __shared__ float macc[SPLIT][16][68];
  __shared__ float mml[SPLIT][16];
  __shared__ float mll[SPLIT][16];

  const int nb8 = gridDim.x >> 3;
  const int bq = ((gridDim.x & 7) == 0) ? ((blockIdx.x & 7) * nb8 + (blockIdx.x >> 3))
                                        : blockIdx.x;
  const int q0 = bq * 16;
  const int w = threadIdx.x >> 6;
  const int lane = threadIdx.x & 63;
  const int q16 = lane & 15;
  const int g = lane >> 4;
  const int g8 = g * 8;

  const int myb = qc[q0 + q16];
  const int lo_q = seg[myb];
  const int hi_q = seg[8 + myb];
  const int bfirst = __shfl(myb, 0);
  const int blast  = __shfl(myb, 15);
  const int kv_lo  = __shfl(lo_q, 0);
  const int kv_hi  = __shfl(hi_q, 15);
  const bool uniformb = (bfirst == blast);

  bf16x8 qf0, qf1;
  {
    const float* qrow = qf + (size_t)(q0 + q16) * 64 + g8;
    float4 x0 = *(const float4*)(qrow);
    float4 x1 = *(const float4*)(qrow + 4);
    float4 x2 = *(const float4*)(qrow + 32);
    float4 x3 = *(const float4*)(qrow + 36);
    qf0[0]=(short)f2bf(x0.x*QSCALE); qf0[1]=(short)f2bf(x0.y*QSCALE);
    qf0[2]=(short)f2bf(x0.z*QSCALE); qf0[3]=(short)f2bf(x0.w*QSCALE);
    qf0[4]=(short)f2bf(x1.x*QSCALE); qf0[5]=(short)f2bf(x1.y*QSCALE);
    qf0[6]=(short)f2bf(x1.z*QSCALE); qf0[7]=(short)f2bf(x1.w*QSCALE);
    qf1[0]=(short)f2bf(x2.x*QSCALE); qf1[1]=(short)f2bf(x2.y*QSCALE);
    qf1[2]=(short)f2bf(x2.z*QSCALE); qf1[3]=(short)f2bf(x2.w*QSCALE);
    qf1[4]=(short)f2bf(x3.x*QSCALE); qf1[5]=(short)f2bf(x3.y*QSCALE);
    qf1[6]=(short)f2bf(x3.z*QSCALE); qf1[7]=(short)f2bf(x3.w*QSCALE);
  }

  const int base = kv_lo & ~31;
  const int nblk = (kv_hi - base + 31) >> 5;
  const int b0 = (nblk * w) / SPLIT;
  const int b1 = (nblk * (w + 1)) / SPLIT;
  const int rowoff = ((q16 >> 2) << 3) + (q16 & 3);

  f32x4 acc0, acc1, acc2, acc3;
  float m, l;

#pragma clang loop unroll(disable)
  for (int rep = 0; rep < REPS; ++rep) {
    f32x4 zz = {0, 0, 0, 0};
    acc0 = zz; acc0[0] = (float)rep * 1e-30f;   // block cross-rep dedupe; 0 for rep 0
    acc1 = zz; acc2 = zz; acc3 = zz;
    m = CONST_M;
    l = 0.0f;

    bf16x8 kA0, kA1, kA2, kA3, kB0, kB1, kB2, kB3;
    bf16x8 vA0, vA1, vA2, vA3, vB0, vB1, vB2, vB3;
    int b = b0;
    if (b < b1) {
      LOADK(A, base + b * 32);
      LOADV(A, base + b * 32);
      while (true) {
        if (b + 1 < b1) { LOADK(B, base + (b + 1) * 32); LOADV(B, base + (b + 1) * 32); }
        DIAG_STEP(A, base + b * 32);
        ++b; if (b >= b1) break;
        if (b + 1 < b1) { LOADK(A, base + (b + 1) * 32); LOADV(A, base + (b + 1) * 32); }
        DIAG_STEP(B, base + b * 32);
        ++b; if (b >= b1) break;
      }
    }
    // keep per-rep results live so earlier reps aren't DCE'd (rule 17)
    asm volatile("" :: "v"(l), "v"(m));
    KEEP4(acc0); KEEP4(acc1); KEEP4(acc2); KEEP4(acc3);
  }

  l += __shfl_xor(l, 16);
  l += __shfl_xor(l, 32);

#pragma unroll
  for (int r = 0; r < 4; ++r) {
    macc[w][q16][0  + g * 4 + r] = acc0[r];
    macc[w][q16][16 + g * 4 + r] = acc1[r];
    macc[w][q16][32 + g * 4 + r] = acc2[r];
    macc[w][q16][48 + g * 4 + r] = acc3[r];
  }
  if (g == 0) { mml[w][q16] = m; mll[w][q16] = l; }
  __syncthreads();

  {
    const int t = threadIdx.x;
    const int i = t >> 4;
    const int c0 = (t & 15) * 4;
    float mstar = NEG_INF;
#pragma unroll
    for (int ww = 0; ww < SPLIT; ++ww) mstar = fmaxf(mstar, mml[ww][i]);
    float s[SPLIT];
    float L = 0.0f;
#pragma unroll
    for (int ww = 0; ww < SPLIT; ++ww) {
      float mw = mml[ww][i];
      s[ww] = __builtin_exp2f(mw - mstar);
      L += s[ww] * mll[ww][i];
    }
    float inv = (L > 0.0f) ? 1.0f / L : 0.0f;
    f32x4 num = {0, 0, 0, 0};
#pragma unroll
    for (int ww = 0; ww < SPLIT; ++ww) {
      f32x4 a = *(const f32x4*)&macc[ww][i][c0];
      num[0] += s[ww] * a[0]; num[1] += s[ww] * a[1];
      num[2] += s[ww] * a[2]; num[3] += s[ww] * a[3];
    }
    float* o = out + (size_t)(q0 + i) * 64 + c0;
    o[0] = num[0] * inv; o[1] = num[1] * inv;
    o[2] = num[2] * inv; o[3] = num[3] * inv;
  }
}

extern "C" void kernel_launch(void* const* d_in, const int* in_sizes, int n_in,
                              void* d_out, int out_size, void* d_ws, size_t ws_size,
                              hipStream_t stream) {
  const float* q  = (const float*)d_in[0];
  const float* kv = (const float*)d_in[1];
  const int* qc   = (const int*)d_in[2];
  const int* kvc  = (const int*)d_in[3];
  float* out = (float*)d_out;

  const int C = 64;
  const int n1 = in_sizes[0] / C;   // 8192
  const int n2 = in_sizes[1] / C;   // 8192

  char* ws = (char*)d_ws;
  size_t off = 0;
  unsigned short* kvb = (unsigned short*)(ws + off); off += (size_t)n2 * C * 2;
  unsigned short* kvt = (unsigned short*)(ws + off); off += (size_t)n2 * C * 2;
  int* seg = (int*)(ws + off); off += 256;
  float* diag = (float*)(ws + off);              // scratch sink for diagnostics

  prep_kv_kernel<<<n2 / 32, 256, 0, stream>>>(kv, kvc, kvb, kvt, seg, n2);
  // diagnostics (REPS=4 so they surface in rocprof top-5 with full counters)
  attn_kernel<0, 4><<<n1 / 16, 256, 0, stream>>>(q, kvb, kvt, qc, seg, diag, n2);
  attn_kernel<1, 4><<<n1 / 16, 256, 0, stream>>>(q, kvb, kvt, qc, seg, diag, n2);
  attn_kernel<2, 4><<<n1 / 16, 256, 0, stream>>>(q, kvb, kvt, qc, seg, diag, n2);
  // the real run (writes d_out)
  attn_kernel<0, 1><<<n1 / 16, 256, 0, stream>>>(q, kvb, kvt, qc, seg, out, n2);
}

// Round 10
// 32.229 us; speedup vs baseline: 7.3095x; 7.3095x over previous
//
#include <hip/hip_runtime.h>
#include <hip/hip_bf16.h>

typedef __attribute__((ext_vector_type(8))) short bf16x8;
typedef __attribute__((ext_vector_type(4))) unsigned short u16x4;
typedef __attribute__((ext_vector_type(4))) float f32x4;

#define NEG_INF (-__builtin_inff())
#define QSCALE (0.125f * 1.4426950408889634f)   // 1/sqrt(64) * log2(e); exp2 domain
#define CONST_M 12.0f                            // safe upper bound on exp2-domain scores

static __device__ __forceinline__ unsigned short f2bf(float x) {
  union { float f; unsigned u; } v; v.f = x;
  unsigned r = (v.u + 0x7fffu + ((v.u >> 16) & 1u)) >> 16;
  return (unsigned short)r;
}

// ---- prep: 16 KV rows/block -> bf16 row-major + blocked transpose kvt[blk32][64][32];
// ---- fused segment-boundary detection: seg[b]=start, seg[8+b]=end ----
__global__ __launch_bounds__(256) void prep_kv_kernel(
    const float* __restrict__ kv, const int* __restrict__ kvc,
    unsigned short* __restrict__ kvb, unsigned short* __restrict__ kvt,
    int* __restrict__ seg, int nkv) {
  __shared__ unsigned short tile[16][64];
  const int nb8 = gridDim.x >> 3;
  const int bp = ((gridDim.x & 7) == 0) ? ((blockIdx.x & 7) * nb8 + (blockIdx.x >> 3))
                                        : blockIdx.x;
  const int rowbase = bp * 16;
  const int t = threadIdx.x;
  if (t < 16) {
    int i = rowbase + t;
    if (i < nkv) {
      int c = kvc[i];
      int cp = (i == 0) ? -1 : kvc[i - 1];
      if (c != cp) {
        for (int b = cp + 1; b <= c; ++b) seg[b] = i;
        if (i == 0) for (int b = 0; b < c; ++b) seg[8 + b] = 0;
      }
      int cn = (i == nkv - 1) ? 8 : kvc[i + 1];
      if (c != cn) {
        for (int b = c; b < cn; ++b) seg[8 + b] = i + 1;
        if (i == nkv - 1) for (int b = c + 1; b < 8; ++b) seg[b] = nkv;
      }
    }
  }
  const int r = t >> 4;               // 0..15
  const int c = (t & 15) * 4;         // 0..60
  float4 a = *(const float4*)(kv + (size_t)(rowbase + r) * 64 + c);
  u16x4 v4;
  v4[0] = f2bf(a.x); v4[1] = f2bf(a.y); v4[2] = f2bf(a.z); v4[3] = f2bf(a.w);
  *(u16x4*)(kvb + (size_t)(rowbase + r) * 64 + c) = v4;
  *(u16x4*)&tile[r][c] = v4;
  __syncthreads();
  const int d = t & 63;               // feature
  const int k0 = (t >> 6) * 4;        // 0/4/8/12
  u16x4 wv;
#pragma unroll
  for (int j = 0; j < 4; ++j) wv[j] = tile[k0 + j][d];
  const int blk = rowbase >> 5;
  const int kbase = (rowbase & 31) + k0;   // which half of the 32-row block
  *(u16x4*)(kvt + (size_t)blk * 2048 + d * 32 + kbase) = wv;
}

// K fragments for block at kv index kvx, row-permuted (ping-pong set P)
#define LOADK(P, kvx)                                                          \
  {                                                                            \
    const unsigned short* kb_ = kvb + (((size_t)((kvx) + rowoff)) << 6) + g8;  \
    k##P##0 = *(const bf16x8*)(kb_);                                           \
    k##P##1 = *(const bf16x8*)(kb_ + 32);                                      \
    k##P##2 = *(const bf16x8*)(kb_ + 256);                                     \
    k##P##3 = *(const bf16x8*)(kb_ + 256 + 32);                                \
  }

#define LOADV(P, kvx)                                                          \
  {                                                                            \
    const unsigned short* vb_ = kvt + (((size_t)(kvx) >> 5) << 11) + q16 * 32 + g8; \
    v##P##0 = *(const bf16x8*)(vb_);                                           \
    v##P##1 = *(const bf16x8*)(vb_ + 512);                                     \
    v##P##2 = *(const bf16x8*)(vb_ + 1024);                                    \
    v##P##3 = *(const bf16x8*)(vb_ + 1536);                                    \
  }

#define COMPUTE(P, kvx)                                                        \
  {                                                                            \
    const int kv0_ = (kvx);                                                    \
    f32x4 z_ = {0, 0, 0, 0};                                                   \
    __builtin_amdgcn_s_setprio(1);                                             \
    f32x4 sT0 = __builtin_amdgcn_mfma_f32_16x16x32_bf16(k##P##0, qf0, z_, 0, 0, 0); \
    sT0 = __builtin_amdgcn_mfma_f32_16x16x32_bf16(k##P##1, qf1, sT0, 0, 0, 0); \
    f32x4 sT1 = __builtin_amdgcn_mfma_f32_16x16x32_bf16(k##P##2, qf0, z_, 0, 0, 0); \
    sT1 = __builtin_amdgcn_mfma_f32_16x16x32_bf16(k##P##3, qf1, sT1, 0, 0, 0); \
    __builtin_amdgcn_s_setprio(0);                                             \
    float v_[8];                                                               \
    const bool full_ = uniformb && (kv0_ >= kv_lo) && (kv0_ + 32 <= kv_hi);    \
    if (full_) {                                                               \
      _Pragma("unroll") for (int r = 0; r < 4; ++r) {                          \
        v_[r] = sT0[r];                                                        \
        v_[4 + r] = sT1[r];                                                    \
      }                                                                        \
    } else {                                                                   \
      const int k0_ = kv0_ + g8;                                               \
      _Pragma("unroll") for (int r = 0; r < 4; ++r) {                          \
        v_[r]     = (k0_ + r     >= lo_q && k0_ + r     < hi_q) ? sT0[r] : NEG_INF; \
        v_[4 + r] = (k0_ + r + 4 >= lo_q && k0_ + r + 4 < hi_q) ? sT1[r] : NEG_INF; \
      }                                                                        \
    }                                                                          \
    float t_ = fmaxf(fmaxf(fmaxf(v_[0], v_[1]), fmaxf(v_[2], v_[3])),          \
                     fmaxf(fmaxf(v_[4], v_[5]), fmaxf(v_[6], v_[7])));         \
    if (__builtin_expect(__any(t_ > m), 0)) {                                  \
      float tt_ = fmaxf(t_, __shfl_xor(t_, 16));                               \
      tt_ = fmaxf(tt_, __shfl_xor(tt_, 32));                                   \
      float mn_ = fmaxf(m, tt_);                                               \
      float f_ = __builtin_exp2f(m - mn_);                                     \
      l *= f_;                                                                 \
      _Pragma("unroll") for (int r = 0; r < 4; ++r) {                          \
        acc0[r] *= f_; acc1[r] *= f_; acc2[r] *= f_; acc3[r] *= f_;            \
      }                                                                        \
      m = mn_;                                                                 \
    }                                                                          \
    float e_[8];                                                               \
    _Pragma("unroll") for (int i = 0; i < 8; ++i)                              \
      e_[i] = __builtin_exp2f(v_[i] - m);   /* exp2(-inf)=0: no guard */       \
    l += (((e_[0] + e_[1]) + (e_[2] + e_[3])) +                                \
          ((e_[4] + e_[5]) + (e_[6] + e_[7])));                                \
    bf16x8 pa_;                                                                \
    _Pragma("unroll") for (int j = 0; j < 8; ++j) pa_[j] = (short)f2bf(e_[j]); \
    __builtin_amdgcn_s_setprio(1);                                             \
    acc0 = __builtin_amdgcn_mfma_f32_16x16x32_bf16(v##P##0, pa_, acc0, 0, 0, 0); \
    acc1 = __builtin_amdgcn_mfma_f32_16x16x32_bf16(v##P##1, pa_, acc1, 0, 0, 0); \
    acc2 = __builtin_amdgcn_mfma_f32_16x16x32_bf16(v##P##2, pa_, acc2, 0, 0, 0); \
    acc3 = __builtin_amdgcn_mfma_f32_16x16x32_bf16(v##P##3, pa_, acc3, 0, 0, 0); \
    __builtin_amdgcn_s_setprio(0);                                             \
  }

// ---- attn partial pass: block = 64 queries (4 waves x 16q subtiles, SAME KV
// ---- stream -> L1 sharing), KV split nc ways ACROSS blocks; writes partials ----
__global__ __launch_bounds__(256, 2) void attn_kernel(
    const float* __restrict__ qf,            // [n1][64] f32
    const unsigned short* __restrict__ kvb,  // [n2][64] bf16
    const unsigned short* __restrict__ kvt,  // [n2/32][64][32] bf16
    const int* __restrict__ qc,
    const int* __restrict__ seg,
    float* __restrict__ pacc,                // [n1][nc][64] f32
    float2* __restrict__ pml,                // [n1][nc] {m,l}
    int n2, int ncl2)
{
  const int nc = 1 << ncl2;
  // decode block -> (q-tile of 64, kv-chunk); batch-affine XCD mapping
  const int per8 = gridDim.x >> 3;
  const int ii = ((gridDim.x & 7) == 0) ? ((blockIdx.x & 7) * per8 + (blockIdx.x >> 3))
                                        : blockIdx.x;
  const int qt = ii >> ncl2;
  const int c  = ii & (nc - 1);
  const int qbase = qt * 64;

  const int w = threadIdx.x >> 6;          // 0..3 : q-subtile
  const int lane = threadIdx.x & 63;
  const int q16 = lane & 15;
  const int g = lane >> 4;
  const int g8 = g * 8;
  const int q0w = qbase + w * 16;          // this wave's 16 queries

  // per-lane segment bounds for this lane's q-row
  const int myb = qc[q0w + q16];
  const int lo_q = seg[myb];
  const int hi_q = seg[8 + myb];
  const int bfirst = __shfl(myb, 0);
  const int blast  = __shfl(myb, 15);
  const int kv_lo  = __shfl(lo_q, 0);
  const int kv_hi  = __shfl(hi_q, 15);
  const bool uniformb = (bfirst == blast);

  // Q B-fragments (scale*log2e folded): B[feat=8g+j][q=q16]
  bf16x8 qf0, qf1;
  {
    const float* qrow = qf + (size_t)(q0w + q16) * 64 + g8;
    float4 x0 = *(const float4*)(qrow);
    float4 x1 = *(const float4*)(qrow + 4);
    float4 x2 = *(const float4*)(qrow + 32);
    float4 x3 = *(const float4*)(qrow + 36);
    qf0[0]=(short)f2bf(x0.x*QSCALE); qf0[1]=(short)f2bf(x0.y*QSCALE);
    qf0[2]=(short)f2bf(x0.z*QSCALE); qf0[3]=(short)f2bf(x0.w*QSCALE);
    qf0[4]=(short)f2bf(x1.x*QSCALE); qf0[5]=(short)f2bf(x1.y*QSCALE);
    qf0[6]=(short)f2bf(x1.z*QSCALE); qf0[7]=(short)f2bf(x1.w*QSCALE);
    qf1[0]=(short)f2bf(x2.x*QSCALE); qf1[1]=(short)f2bf(x2.y*QSCALE);
    qf1[2]=(short)f2bf(x2.z*QSCALE); qf1[3]=(short)f2bf(x2.w*QSCALE);
    qf1[4]=(short)f2bf(x3.x*QSCALE); qf1[5]=(short)f2bf(x3.y*QSCALE);
    qf1[6]=(short)f2bf(x3.z*QSCALE); qf1[7]=(short)f2bf(x3.w*QSCALE);
  }

  const int base = kv_lo & ~31;
  const int nblk = (kv_hi - base + 31) >> 5;
  const int b0 = (nblk * c) >> ncl2;
  const int b1 = (nblk * (c + 1)) >> ncl2;

  // K-row permutation: A row i (=q16) of sub-tile s reads kv row kv0 + 8*(i>>2)+(i&3) + 4s
  const int rowoff = ((q16 >> 2) << 3) + (q16 & 3);

  f32x4 acc0 = {0,0,0,0}, acc1 = {0,0,0,0}, acc2 = {0,0,0,0}, acc3 = {0,0,0,0};
  float m = CONST_M;
  float l = 0.0f;

  bf16x8 kA0, kA1, kA2, kA3, kB0, kB1, kB2, kB3;
  bf16x8 vA0, vA1, vA2, vA3, vB0, vB1, vB2, vB3;
  int b = b0;
  if (b < b1) {
    LOADK(A, base + b * 32);
    LOADV(A, base + b * 32);
    while (true) {
      if (b + 1 < b1) { LOADK(B, base + (b + 1) * 32); LOADV(B, base + (b + 1) * 32); }
      COMPUTE(A, base + b * 32);
      ++b; if (b >= b1) break;
      if (b + 1 < b1) { LOADK(A, base + (b + 1) * 32); LOADV(A, base + (b + 1) * 32); }
      COMPUTE(B, base + b * 32);
      ++b; if (b >= b1) break;
    }
  }

  // cross-g reduce of l (m already uniform across the wave)
  l += __shfl_xor(l, 16);
  l += __shfl_xor(l, 32);

  // write partials (no LDS, no syncthreads — waves fully independent)
  const int row = q0w + q16;
  float* pr = pacc + ((size_t)row * nc + c) * 64;
  *(f32x4*)(pr + 0  + g * 4) = acc0;
  *(f32x4*)(pr + 16 + g * 4) = acc1;
  *(f32x4*)(pr + 32 + g * 4) = acc2;
  *(f32x4*)(pr + 48 + g * 4) = acc3;
  if (g == 0) {
    float2 v; v.x = m; v.y = l;
    pml[(size_t)row * nc + c] = v;
  }
}

// ---- merge nc chunk-partials per q-row ----
__global__ __launch_bounds__(256) void merge_kernel(
    const float* __restrict__ pacc, const float2* __restrict__ pml,
    float* __restrict__ out, int ncl2)
{
  const int nc = 1 << ncl2;
  const int nb8 = gridDim.x >> 3;
  const int bq = ((gridDim.x & 7) == 0) ? ((blockIdx.x & 7) * nb8 + (blockIdx.x >> 3))
                                        : blockIdx.x;
  const int q0 = bq * 16;
  const int t = threadIdx.x;
  const int i = t >> 4;
  const int c0 = (t & 15) * 4;
  const int R = q0 + i;

  float mm[4], ll[4], sc[4];
  float mstar = NEG_INF;
#pragma unroll
  for (int cc = 0; cc < 4; ++cc) if (cc < nc) {
    float2 v = pml[(size_t)R * nc + cc];
    mm[cc] = v.x; ll[cc] = v.y;
    mstar = fmaxf(mstar, v.x);
  }
  float L = 0.0f;
#pragma unroll
  for (int cc = 0; cc < 4; ++cc) if (cc < nc) {
    sc[cc] = __builtin_exp2f(mm[cc] - mstar);
    L += sc[cc] * ll[cc];
  }
  float inv = (L > 0.0f) ? 1.0f / L : 0.0f;
  f32x4 num = {0, 0, 0, 0};
#pragma unroll
  for (int cc = 0; cc < 4; ++cc) if (cc < nc) {
    f32x4 a = *(const f32x4*)&pacc[((size_t)R * nc + cc) * 64 + c0];
    num[0] += sc[cc] * a[0]; num[1] += sc[cc] * a[1];
    num[2] += sc[cc] * a[2]; num[3] += sc[cc] * a[3];
  }
  f32x4 o;
  o[0] = num[0] * inv; o[1] = num[1] * inv;
  o[2] = num[2] * inv; o[3] = num[3] * inv;
  *(f32x4*)&out[(size_t)R * 64 + c0] = o;
}

extern "C" void kernel_launch(void* const* d_in, const int* in_sizes, int n_in,
                              void* d_out, int out_size, void* d_ws, size_t ws_size,
                              hipStream_t stream) {
  const float* q  = (const float*)d_in[0];
  const float* kv = (const float*)d_in[1];
  const int* qc   = (const int*)d_in[2];
  const int* kvc  = (const int*)d_in[3];
  float* out = (float*)d_out;

  const int C = 64;
  const int n1 = in_sizes[0] / C;   // 8192
  const int n2 = in_sizes[1] / C;   // 8192

  // choose kv-split width from available workspace (observed ws ~268MB -> nc=4)
  const size_t fixed = (size_t)n2 * C * 2 * 2 + 4096;   // kvb + kvt + seg pad
  int ncl2 = 0;
  if (ws_size >= fixed + (size_t)n1 * 4 * (64 * 4 + 8)) ncl2 = 2;
  else if (ws_size >= fixed + (size_t)n1 * 2 * (64 * 4 + 8)) ncl2 = 1;
  const int nc = 1 << ncl2;

  char* ws = (char*)d_ws;
  size_t off = 0;
  unsigned short* kvb = (unsigned short*)(ws + off); off += (size_t)n2 * C * 2;
  unsigned short* kvt = (unsigned short*)(ws + off); off += (size_t)n2 * C * 2;
  int* seg = (int*)(ws + off); off += 4096;
  float* pacc = (float*)(ws + off); off += (size_t)n1 * nc * 64 * 4;
  float2* pml = (float2*)(ws + off);

  prep_kv_kernel<<<n2 / 16, 256, 0, stream>>>(kv, kvc, kvb, kvt, seg, n2);
  attn_kernel<<<(n1 / 64) * nc, 256, 0, stream>>>(q, kvb, kvt, qc, seg, pacc, pml, n2, ncl2);
  merge_kernel<<<n1 / 16, 256, 0, stream>>>(pacc, pml, out, ncl2);
}

// Round 11
// 29.649 us; speedup vs baseline: 7.9456x; 1.0870x over previous
//
#include <hip/hip_runtime.h>
#include <hip/hip_bf16.h>

typedef __attribute__((ext_vector_type(8))) short bf16x8;
typedef __attribute__((ext_vector_type(4))) unsigned short u16x4;
typedef __attribute__((ext_vector_type(4))) float f32x4;

#define NEG_INF (-__builtin_inff())
#define QSCALE (0.125f * 1.4426950408889634f)   // 1/sqrt(64) * log2(e); exp2 domain
#define CONST_M 12.0f                            // safe upper bound on exp2-domain scores

static __device__ __forceinline__ unsigned short f2bf(float x) {
  union { float f; unsigned u; } v; v.f = x;
  unsigned r = (v.u + 0x7fffu + ((v.u >> 16) & 1u)) >> 16;
  return (unsigned short)r;
}

// ---- prep: 16 KV rows/block -> bf16 row-major + blocked transpose kvt[blk32][64][32];
// ---- fused segment-boundary detection: seg[b]=start, seg[8+b]=end ----
__global__ __launch_bounds__(256) void prep_kv_kernel(
    const float* __restrict__ kv, const int* __restrict__ kvc,
    unsigned short* __restrict__ kvb, unsigned short* __restrict__ kvt,
    int* __restrict__ seg, int nkv) {
  __shared__ unsigned short tile[16][64];
  const int nb8 = gridDim.x >> 3;
  const int bp = ((gridDim.x & 7) == 0) ? ((blockIdx.x & 7) * nb8 + (blockIdx.x >> 3))
                                        : blockIdx.x;
  const int rowbase = bp * 16;
  const int t = threadIdx.x;
  if (t < 16) {
    int i = rowbase + t;
    if (i < nkv) {
      int c = kvc[i];
      int cp = (i == 0) ? -1 : kvc[i - 1];
      if (c != cp) {
        for (int b = cp + 1; b <= c; ++b) seg[b] = i;
        if (i == 0) for (int b = 0; b < c; ++b) seg[8 + b] = 0;
      }
      int cn = (i == nkv - 1) ? 8 : kvc[i + 1];
      if (c != cn) {
        for (int b = c; b < cn; ++b) seg[8 + b] = i + 1;
        if (i == nkv - 1) for (int b = c + 1; b < 8; ++b) seg[b] = nkv;
      }
    }
  }
  const int r = t >> 4;
  const int c = (t & 15) * 4;
  float4 a = *(const float4*)(kv + (size_t)(rowbase + r) * 64 + c);
  u16x4 v4;
  v4[0] = f2bf(a.x); v4[1] = f2bf(a.y); v4[2] = f2bf(a.z); v4[3] = f2bf(a.w);
  *(u16x4*)(kvb + (size_t)(rowbase + r) * 64 + c) = v4;
  *(u16x4*)&tile[r][c] = v4;
  __syncthreads();
  const int d = t & 63;
  const int k0 = (t >> 6) * 4;
  u16x4 wv;
#pragma unroll
  for (int j = 0; j < 4; ++j) wv[j] = tile[k0 + j][d];
  const int blk = rowbase >> 5;
  const int kbase = (rowbase & 31) + k0;
  *(u16x4*)(kvt + (size_t)blk * 2048 + d * 32 + kbase) = wv;
}

// K fragments (row-permuted), ping-pong set P
#define LOADK(P, kvx)                                                          \
  {                                                                            \
    const unsigned short* kb_ = kvb + (((size_t)((kvx) + rowoff)) << 6) + g8;  \
    k##P##0 = *(const bf16x8*)(kb_);                                           \
    k##P##1 = *(const bf16x8*)(kb_ + 32);                                      \
    k##P##2 = *(const bf16x8*)(kb_ + 256);                                     \
    k##P##3 = *(const bf16x8*)(kb_ + 256 + 32);                                \
  }

// per-subtile softmax + P-pack: scores s0_,s1_ -> pa_, state mS,lS, bounds loS,hiS
#define SOFTMAX_PACK(s0_, s1_, mS, lS, loS, hiS, pa_)                          \
  {                                                                            \
    float v_[8];                                                               \
    if (full_) {                                                               \
      _Pragma("unroll") for (int r = 0; r < 4; ++r) {                          \
        v_[r] = s0_[r]; v_[4 + r] = s1_[r];                                    \
      }                                                                        \
    } else {                                                                   \
      _Pragma("unroll") for (int r = 0; r < 4; ++r) {                          \
        v_[r]     = (k0_ + r     >= loS && k0_ + r     < hiS) ? s0_[r] : NEG_INF; \
        v_[4 + r] = (k0_ + r + 4 >= loS && k0_ + r + 4 < hiS) ? s1_[r] : NEG_INF; \
      }                                                                        \
    }                                                                          \
    float t_ = fmaxf(fmaxf(fmaxf(v_[0], v_[1]), fmaxf(v_[2], v_[3])),          \
                     fmaxf(fmaxf(v_[4], v_[5]), fmaxf(v_[6], v_[7])));         \
    if (__builtin_expect(__any(t_ > mS), 0)) {                                 \
      float tt_ = fmaxf(t_, __shfl_xor(t_, 16));                               \
      tt_ = fmaxf(tt_, __shfl_xor(tt_, 32));                                   \
      float mn_ = fmaxf(mS, tt_);                                              \
      float f_ = __builtin_exp2f(mS - mn_);                                    \
      lS *= f_;                                                                \
      _Pragma("unroll") for (int r = 0; r < 4; ++r) {                          \
        acc##pa_##0[r] *= f_; acc##pa_##1[r] *= f_;                            \
        acc##pa_##2[r] *= f_; acc##pa_##3[r] *= f_;                            \
      }                                                                        \
      mS = mn_;                                                                \
    }                                                                          \
    float e_[8];                                                               \
    _Pragma("unroll") for (int i = 0; i < 8; ++i)                              \
      e_[i] = __builtin_exp2f(v_[i] - mS);                                     \
    lS += (((e_[0] + e_[1]) + (e_[2] + e_[3])) +                               \
           ((e_[4] + e_[5]) + (e_[6] + e_[7])));                               \
    _Pragma("unroll") for (int j = 0; j < 8; ++j)                              \
      pab##pa_[j] = (short)f2bf(e_[j]);                                        \
  }

// one 32-kv-row step for BOTH 16-q subtiles, sharing K (set P) and V fragments
#define STEP(P, kvx)                                                           \
  {                                                                            \
    const int kv0_ = (kvx);                                                    \
    const unsigned short* vb_ = kvt + (((size_t)kv0_ >> 5) << 11) + q16 * 32 + g8; \
    bf16x8 vf0_ = *(const bf16x8*)(vb_);                                       \
    bf16x8 vf1_ = *(const bf16x8*)(vb_ + 512);                                 \
    bf16x8 vf2_ = *(const bf16x8*)(vb_ + 1024);                                \
    bf16x8 vf3_ = *(const bf16x8*)(vb_ + 1536);                                \
    f32x4 z_ = {0, 0, 0, 0};                                                   \
    __builtin_amdgcn_s_setprio(1);                                             \
    f32x4 s00 = __builtin_amdgcn_mfma_f32_16x16x32_bf16(k##P##0, q00, z_, 0, 0, 0); \
    s00 = __builtin_amdgcn_mfma_f32_16x16x32_bf16(k##P##1, q01, s00, 0, 0, 0); \
    f32x4 s01 = __builtin_amdgcn_mfma_f32_16x16x32_bf16(k##P##2, q00, z_, 0, 0, 0); \
    s01 = __builtin_amdgcn_mfma_f32_16x16x32_bf16(k##P##3, q01, s01, 0, 0, 0); \
    f32x4 s10 = __builtin_amdgcn_mfma_f32_16x16x32_bf16(k##P##0, q10, z_, 0, 0, 0); \
    s10 = __builtin_amdgcn_mfma_f32_16x16x32_bf16(k##P##1, q11, s10, 0, 0, 0); \
    f32x4 s11 = __builtin_amdgcn_mfma_f32_16x16x32_bf16(k##P##2, q10, z_, 0, 0, 0); \
    s11 = __builtin_amdgcn_mfma_f32_16x16x32_bf16(k##P##3, q11, s11, 0, 0, 0); \
    __builtin_amdgcn_s_setprio(0);                                             \
    const bool full_ = uniformb && (kv0_ >= kv_lo) && (kv0_ + 32 <= kv_hi);    \
    const int k0_ = kv0_ + g8;                                                 \
    bf16x8 pab0, pab1;                                                         \
    SOFTMAX_PACK(s00, s01, m0, l0, lo0, hi0, 0)                                \
    SOFTMAX_PACK(s10, s11, m1, l1, lo1, hi1, 1)                                \
    __builtin_amdgcn_s_setprio(1);                                             \
    acc00 = __builtin_amdgcn_mfma_f32_16x16x32_bf16(vf0_, pab0, acc00, 0, 0, 0); \
    acc01 = __builtin_amdgcn_mfma_f32_16x16x32_bf16(vf1_, pab0, acc01, 0, 0, 0); \
    acc02 = __builtin_amdgcn_mfma_f32_16x16x32_bf16(vf2_, pab0, acc02, 0, 0, 0); \
    acc03 = __builtin_amdgcn_mfma_f32_16x16x32_bf16(vf3_, pab0, acc03, 0, 0, 0); \
    acc10 = __builtin_amdgcn_mfma_f32_16x16x32_bf16(vf0_, pab1, acc10, 0, 0, 0); \
    acc11 = __builtin_amdgcn_mfma_f32_16x16x32_bf16(vf1_, pab1, acc11, 0, 0, 0); \
    acc12 = __builtin_amdgcn_mfma_f32_16x16x32_bf16(vf2_, pab1, acc12, 0, 0, 0); \
    acc13 = __builtin_amdgcn_mfma_f32_16x16x32_bf16(vf3_, pab1, acc13, 0, 0, 0); \
    __builtin_amdgcn_s_setprio(0);                                             \
  }

// ---- attn partials: wave = 32 queries (2 subtiles share every K/V fragment ->
// ---- half the load bytes per query); KV split nc ways across blocks ----
__global__ __launch_bounds__(256, 2) void attn_kernel(
    const float* __restrict__ qf,            // [n1][64] f32
    const unsigned short* __restrict__ kvb,  // [n2][64] bf16
    const unsigned short* __restrict__ kvt,  // [n2/32][64][32] bf16
    const int* __restrict__ qc,
    const int* __restrict__ seg,
    float* __restrict__ pacc,                // [n1][nc][64] f32
    float2* __restrict__ pml,                // [n1][nc] {m,l}
    int n2, int ncl2)
{
  const int nc = 1 << ncl2;
  const int per8 = gridDim.x >> 3;
  const int ii = ((gridDim.x & 7) == 0) ? ((blockIdx.x & 7) * per8 + (blockIdx.x >> 3))
                                        : blockIdx.x;
  const int qt = ii >> ncl2;                // 128-query tile
  const int c  = ii & (nc - 1);             // kv chunk
  const int qbase = qt << 7;

  const int w = threadIdx.x >> 6;           // 0..3
  const int lane = threadIdx.x & 63;
  const int q16 = lane & 15;
  const int g = lane >> 4;
  const int g8 = g * 8;
  const int q0w = qbase + w * 32;           // this wave's 32 queries

  // per-lane segment bounds, both subtiles
  const int myb0 = qc[q0w + q16];
  const int myb1 = qc[q0w + 16 + q16];
  const int lo0 = seg[myb0], hi0 = seg[8 + myb0];
  const int lo1 = seg[myb1], hi1 = seg[8 + myb1];
  const int bfirst = __shfl(myb0, 0);
  const int blast  = __shfl(myb1, 15);
  const int kv_lo  = __shfl(lo0, 0);
  const int kv_hi  = __shfl(hi1, 15);
  const bool uniformb = (bfirst == blast);

  // Q B-fragments for both subtiles (scale*log2e folded)
  bf16x8 q00, q01, q10, q11;
  {
    const float* qr0 = qf + (size_t)(q0w + q16) * 64 + g8;
    const float* qr1 = qf + (size_t)(q0w + 16 + q16) * 64 + g8;
    float4 a0 = *(const float4*)(qr0),     a1 = *(const float4*)(qr0 + 4);
    float4 a2 = *(const float4*)(qr0 + 32), a3 = *(const float4*)(qr0 + 36);
    float4 b0 = *(const float4*)(qr1),     b1 = *(const float4*)(qr1 + 4);
    float4 b2 = *(const float4*)(qr1 + 32), b3 = *(const float4*)(qr1 + 36);
    q00[0]=(short)f2bf(a0.x*QSCALE); q00[1]=(short)f2bf(a0.y*QSCALE);
    q00[2]=(short)f2bf(a0.z*QSCALE); q00[3]=(short)f2bf(a0.w*QSCALE);
    q00[4]=(short)f2bf(a1.x*QSCALE); q00[5]=(short)f2bf(a1.y*QSCALE);
    q00[6]=(short)f2bf(a1.z*QSCALE); q00[7]=(short)f2bf(a1.w*QSCALE);
    q01[0]=(short)f2bf(a2.x*QSCALE); q01[1]=(short)f2bf(a2.y*QSCALE);
    q01[2]=(short)f2bf(a2.z*QSCALE); q01[3]=(short)f2bf(a2.w*QSCALE);
    q01[4]=(short)f2bf(a3.x*QSCALE); q01[5]=(short)f2bf(a3.y*QSCALE);
    q01[6]=(short)f2bf(a3.z*QSCALE); q01[7]=(short)f2bf(a3.w*QSCALE);
    q10[0]=(short)f2bf(b0.x*QSCALE); q10[1]=(short)f2bf(b0.y*QSCALE);
    q10[2]=(short)f2bf(b0.z*QSCALE); q10[3]=(short)f2bf(b0.w*QSCALE);
    q10[4]=(short)f2bf(b1.x*QSCALE); q10[5]=(short)f2bf(b1.y*QSCALE);
    q10[6]=(short)f2bf(b1.z*QSCALE); q10[7]=(short)f2bf(b1.w*QSCALE);
    q11[0]=(short)f2bf(b2.x*QSCALE); q11[1]=(short)f2bf(b2.y*QSCALE);
    q11[2]=(short)f2bf(b2.z*QSCALE); q11[3]=(short)f2bf(b2.w*QSCALE);
    q11[4]=(short)f2bf(b3.x*QSCALE); q11[5]=(short)f2bf(b3.y*QSCALE);
    q11[6]=(short)f2bf(b3.z*QSCALE); q11[7]=(short)f2bf(b3.w*QSCALE);
  }

  const int base = kv_lo & ~31;
  const int nblk = (kv_hi - base + 31) >> 5;
  const int b0i = (nblk * c) >> ncl2;
  const int b1i = (nblk * (c + 1)) >> ncl2;

  const int rowoff = ((q16 >> 2) << 3) + (q16 & 3);

  f32x4 acc00 = {0,0,0,0}, acc01 = {0,0,0,0}, acc02 = {0,0,0,0}, acc03 = {0,0,0,0};
  f32x4 acc10 = {0,0,0,0}, acc11 = {0,0,0,0}, acc12 = {0,0,0,0}, acc13 = {0,0,0,0};
  float m0 = CONST_M, l0 = 0.0f;
  float m1 = CONST_M, l1 = 0.0f;

  bf16x8 kA0, kA1, kA2, kA3, kB0, kB1, kB2, kB3;
  int b = b0i;
  if (b < b1i) {
    LOADK(A, base + b * 32);
    while (true) {
      if (b + 1 < b1i) LOADK(B, base + (b + 1) * 32);
      STEP(A, base + b * 32);
      ++b; if (b >= b1i) break;
      if (b + 1 < b1i) LOADK(A, base + (b + 1) * 32);
      STEP(B, base + b * 32);
      ++b; if (b >= b1i) break;
    }
  }

  // cross-g reduce of l (m already uniform across g for each subtile)
  l0 += __shfl_xor(l0, 16); l0 += __shfl_xor(l0, 32);
  l1 += __shfl_xor(l1, 16); l1 += __shfl_xor(l1, 32);

  const int row0 = q0w + q16;
  const int row1 = q0w + 16 + q16;
  float* pr0 = pacc + ((size_t)row0 * nc + c) * 64;
  float* pr1 = pacc + ((size_t)row1 * nc + c) * 64;
  *(f32x4*)(pr0 + 0  + g * 4) = acc00;
  *(f32x4*)(pr0 + 16 + g * 4) = acc01;
  *(f32x4*)(pr0 + 32 + g * 4) = acc02;
  *(f32x4*)(pr0 + 48 + g * 4) = acc03;
  *(f32x4*)(pr1 + 0  + g * 4) = acc10;
  *(f32x4*)(pr1 + 16 + g * 4) = acc11;
  *(f32x4*)(pr1 + 32 + g * 4) = acc12;
  *(f32x4*)(pr1 + 48 + g * 4) = acc13;
  if (g == 0) {
    float2 v0; v0.x = m0; v0.y = l0;
    float2 v1; v1.x = m1; v1.y = l1;
    pml[(size_t)row0 * nc + c] = v0;
    pml[(size_t)row1 * nc + c] = v1;
  }
}

// ---- merge nc chunk-partials per q-row ----
__global__ __launch_bounds__(256) void merge_kernel(
    const float* __restrict__ pacc, const float2* __restrict__ pml,
    float* __restrict__ out, int ncl2)
{
  const int nc = 1 << ncl2;
  const int nb8 = gridDim.x >> 3;
  const int bq = ((gridDim.x & 7) == 0) ? ((blockIdx.x & 7) * nb8 + (blockIdx.x >> 3))
                                        : blockIdx.x;
  const int q0 = bq * 16;
  const int t = threadIdx.x;
  const int i = t >> 4;
  const int c0 = (t & 15) * 4;
  const int R = q0 + i;

  float mm[8], ll[8], sc[8];
  float mstar = NEG_INF;
#pragma unroll
  for (int cc = 0; cc < 8; ++cc) if (cc < nc) {
    float2 v = pml[(size_t)R * nc + cc];
    mm[cc] = v.x; ll[cc] = v.y;
    mstar = fmaxf(mstar, v.x);
  }
  float L = 0.0f;
#pragma unroll
  for (int cc = 0; cc < 8; ++cc) if (cc < nc) {
    sc[cc] = __builtin_exp2f(mm[cc] - mstar);
    L += sc[cc] * ll[cc];
  }
  float inv = (L > 0.0f) ? 1.0f / L : 0.0f;
  f32x4 num = {0, 0, 0, 0};
#pragma unroll
  for (int cc = 0; cc < 8; ++cc) if (cc < nc) {
    f32x4 a = *(const f32x4*)&pacc[((size_t)R * nc + cc) * 64 + c0];
    num[0] += sc[cc] * a[0]; num[1] += sc[cc] * a[1];
    num[2] += sc[cc] * a[2]; num[3] += sc[cc] * a[3];
  }
  f32x4 o;
  o[0] = num[0] * inv; o[1] = num[1] * inv;
  o[2] = num[2] * inv; o[3] = num[3] * inv;
  *(f32x4*)&out[(size_t)R * 64 + c0] = o;
}

extern "C" void kernel_launch(void* const* d_in, const int* in_sizes, int n_in,
                              void* d_out, int out_size, void* d_ws, size_t ws_size,
                              hipStream_t stream) {
  const float* q  = (const float*)d_in[0];
  const float* kv = (const float*)d_in[1];
  const int* qc   = (const int*)d_in[2];
  const int* kvc  = (const int*)d_in[3];
  float* out = (float*)d_out;

  const int C = 64;
  const int n1 = in_sizes[0] / C;   // 8192
  const int n2 = in_sizes[1] / C;   // 8192

  const size_t fixed = (size_t)n2 * C * 2 * 2 + 4096;   // kvb + kvt + seg pad
  int ncl2 = 0;
  if (ws_size >= fixed + (size_t)n1 * 8 * (64 * 4 + 8)) ncl2 = 3;
  else if (ws_size >= fixed + (size_t)n1 * 4 * (64 * 4 + 8)) ncl2 = 2;
  else if (ws_size >= fixed + (size_t)n1 * 2 * (64 * 4 + 8)) ncl2 = 1;
  const int nc = 1 << ncl2;

  char* ws = (char*)d_ws;
  size_t off = 0;
  unsigned short* kvb = (unsigned short*)(ws + off); off += (size_t)n2 * C * 2;
  unsigned short* kvt = (unsigned short*)(ws + off); off += (size_t)n2 * C * 2;
  int* seg = (int*)(ws + off); off += 4096;
  float* pacc = (float*)(ws + off); off += (size_t)n1 * nc * 64 * 4;
  float2* pml = (float2*)(ws + off);

  prep_kv_kernel<<<n2 / 16, 256, 0, stream>>>(kv, kvc, kvb, kvt, seg, n2);
  attn_kernel<<<(n1 / 128) * nc, 256, 0, stream>>>(q, kvb, kvt, qc, seg, pacc, pml, n2, ncl2);
  merge_kernel<<<n1 / 16, 256, 0, stream>>>(pacc, pml, out, ncl2);
}